// Round 1
// baseline (132.724 us; speedup 1.0000x reference)
//
#include <hip/hip_runtime.h>
#include <math.h>

#define HORIZON 20
#define DT      0.1f
#define EPS     1e-4f
#define V_MAX   0.22f
#define W_MAX   2.8f

// jax.nn.softplus(x) == max(x,0) + log1p(exp(-|x|))
__device__ __forceinline__ float softplus_f(float x) {
    return fmaxf(x, 0.0f) + log1pf(expf(-fabsf(x)));
}

__global__ __launch_bounds__(256) void lqr_kernel(
    const float* __restrict__ ref,     // (B,5) row-major: e0,e1,e2,v_ref,w_ref
    const float* __restrict__ q_raw,   // (3,)
    const float* __restrict__ r_raw,   // (2,)
    const float* __restrict__ qf_raw,  // (3,)
    float* __restrict__ out,           // (B,2)
    int batch)
{
    const int i = blockIdx.x * blockDim.x + threadIdx.x;
    if (i >= batch) return;

    // Batch-uniform params: pointers + indices are wave-uniform -> scalar loads.
    const float q0  = softplus_f(q_raw[0])  + EPS;
    const float q1  = softplus_f(q_raw[1])  + EPS;
    const float q2  = softplus_f(q_raw[2])  + EPS;
    const float r0e = softplus_f(r_raw[0])  + EPS + EPS;  // R diag + eps*I2
    const float r1e = softplus_f(r_raw[1])  + EPS + EPS;
    const float qf0 = softplus_f(qf_raw[0]) + EPS;
    const float qf1 = softplus_f(qf_raw[1]) + EPS;
    const float qf2 = softplus_f(qf_raw[2]) + EPS;

    const float e0   = ref[5*i + 0];
    const float e1   = ref[5*i + 1];
    const float e2   = ref[5*i + 2];
    const float vref = ref[5*i + 3];
    const float wref = ref[5*i + 4];

    const float dt  = DT;
    const float dt2 = dt * dt;
    const float dtw = dt * wref;
    const float dtv = dt * vref;

    // P symmetric: p00 p01 p02 / p01 p11 p12 / p02 p12 p22. P0 = diag(qf).
    float p00 = qf0, p01 = 0.0f, p02 = 0.0f, p11 = qf1, p12 = 0.0f, p22 = qf2;
    float k00 = 0.0f, k01 = 0.0f, k02 = 0.0f, k10 = 0.0f, k11 = 0.0f, k12 = 0.0f;

    // A = [[1, dtw, 0], [-dtw, 1, dtv], [0, 0, 1]]
    // B = [[-dt,0],[0,0],[0,-dt]]
    #pragma unroll 4
    for (int t = 0; t < HORIZON; ++t) {
        // m = (BtP @ A) / (-dt)  (BtP row0 = -dt*P[0,:], row1 = -dt*P[2,:])
        const float m00 = p00 - dtw * p01;
        const float m01 = dtw * p00 + p01;
        const float m02 = dtv * p01 + p02;
        const float m10 = p02 - dtw * p12;
        const float m11 = dtw * p02 + p12;
        const float m12 = dtv * p12 + p22;

        // S = R + eps*I + dt^2 * [[p00, p02],[p02, p22]]
        const float s00 = r0e + dt2 * p00;
        const float s01 =       dt2 * p02;
        const float s11 = r1e + dt2 * p22;
        const float inv_det = 1.0f / (s00 * s11 - s01 * s01);
        const float c = -dt * inv_det;   // fold the -dt of M into K

        // K = S^{-1} (BtP @ A)
        k00 = c * (s11 * m00 - s01 * m10);
        k01 = c * (s11 * m01 - s01 * m11);
        k02 = c * (s11 * m02 - s01 * m12);
        k10 = c * (s00 * m10 - s01 * m00);
        k11 = c * (s00 * m11 - s01 * m01);
        k12 = c * (s00 * m12 - s01 * m02);

        // T = A^T P
        const float t00 = p00 - dtw * p01;
        const float t01 = p01 - dtw * p11;
        const float t02 = p02 - dtw * p12;
        const float t10 = dtw * p00 + p01;
        const float t11 = dtw * p01 + p11;
        const float t12 = dtw * p02 + p12;
        const float t20 = dtv * p01 + p02;
        const float t21 = dtv * p11 + p12;
        const float t22 = dtv * p12 + p22;

        // Acl = A - B@K  (B@K: row0 = -dt*K[0,:], row2 = -dt*K[1,:], row1 = 0)
        const float a00 = 1.0f + dt * k00;
        const float a01 = dtw  + dt * k01;
        const float a02 =        dt * k02;
        const float a20 =        dt * k10;
        const float a21 =        dt * k11;
        const float a22 = 1.0f + dt * k12;
        // Acl row1 = (-dtw, 1, dtv)

        // P_new = Q + T @ Acl  (symmetric: keep upper triangle)
        p00 = q0 + t00 * a00 - t01 * dtw + t02 * a20;
        p01 =      t00 * a01 + t01       + t02 * a21;
        p02 =      t00 * a02 + t01 * dtv + t02 * a22;
        p11 = q1 + t10 * a01 + t11       + t12 * a21;
        p12 =      t10 * a02 + t11 * dtv + t12 * a22;
        p22 = q2 + t20 * a02 + t21 * dtv + t22 * a22;
    }

    // delta_u = -K0 @ error; mean = u_ref + delta_u; clip
    const float du0 = -(k00 * e0 + k01 * e1 + k02 * e2);
    const float du1 = -(k10 * e0 + k11 * e1 + k12 * e2);
    const float v = fminf(fmaxf(vref + du0, -V_MAX), V_MAX);
    const float w = fminf(fmaxf(wref + du1, -W_MAX), W_MAX);

    // coalesced 8B store
    float2* out2 = reinterpret_cast<float2*>(out);
    out2[i] = make_float2(v, w);
}

extern "C" void kernel_launch(void* const* d_in, const int* in_sizes, int n_in,
                              void* d_out, int out_size, void* d_ws, size_t ws_size,
                              hipStream_t stream) {
    const float* ref    = (const float*)d_in[0];
    const float* q_raw  = (const float*)d_in[1];
    const float* r_raw  = (const float*)d_in[2];
    const float* qf_raw = (const float*)d_in[3];
    float* out = (float*)d_out;

    const int batch = in_sizes[0] / 5;
    const int block = 256;
    const int grid  = (batch + block - 1) / block;
    lqr_kernel<<<grid, block, 0, stream>>>(ref, q_raw, r_raw, qf_raw, out, batch);
}

// Round 2
// 97.212 us; speedup vs baseline: 1.3653x; 1.3653x over previous
//
#include <hip/hip_runtime.h>
#include <math.h>

#define HORIZON 20
#define DT      0.1f
#define EPS     1e-4f
#define V_MAX   0.22f
#define W_MAX   2.8f

typedef float v2f __attribute__((ext_vector_type(2)));

// jax.nn.softplus(x) == max(x,0) + log1p(exp(-|x|))
__device__ __forceinline__ float softplus_f(float x) {
    return fmaxf(x, 0.0f) + log1pf(expf(-fabsf(x)));
}

// v_rcp_f32: ~1 ulp approx, 1 instruction (vs ~10-instr IEEE div sequence).
__device__ __forceinline__ v2f rcp2(v2f x) {
    v2f r;
    r.x = __builtin_amdgcn_rcpf(x.x);
    r.y = __builtin_amdgcn_rcpf(x.y);
    return r;
}

__global__ __launch_bounds__(256) void lqr_kernel(
    const float* __restrict__ ref,     // (B,5): e0,e1,e2,v_ref,w_ref
    const float* __restrict__ q_raw,   // (3,)
    const float* __restrict__ r_raw,   // (2,)
    const float* __restrict__ qf_raw,  // (3,)
    float* __restrict__ out,           // (B,2)
    int batch)
{
    const int i = blockIdx.x * blockDim.x + threadIdx.x;  // pair index
    const int i0 = 2 * i;
    if (i0 >= batch) return;
    const bool pair = (i0 + 1 < batch);

    // Batch-uniform params (wave-uniform -> scalar pipe).
    const float q0  = softplus_f(q_raw[0])  + EPS;
    const float q1  = softplus_f(q_raw[1])  + EPS;
    const float q2  = softplus_f(q_raw[2])  + EPS;
    const float r0e = softplus_f(r_raw[0])  + EPS + EPS;  // R diag + eps*I2
    const float r1e = softplus_f(r_raw[1])  + EPS + EPS;
    const float qf0 = softplus_f(qf_raw[0]) + EPS;
    const float qf1 = softplus_f(qf_raw[1]) + EPS;
    const float qf2 = softplus_f(qf_raw[2]) + EPS;

    // Load two elements (10 consecutive floats) as 5x float2 (8B-aligned).
    v2f e0, e1, e2, vref, wref;
    if (pair) {
        const float2* r2 = reinterpret_cast<const float2*>(ref) + 5 * i;
        const float2 d0 = r2[0], d1 = r2[1], d2 = r2[2], d3 = r2[3], d4 = r2[4];
        e0   = (v2f){d0.x, d2.y};
        e1   = (v2f){d0.y, d3.x};
        e2   = (v2f){d1.x, d3.y};
        vref = (v2f){d1.y, d4.x};
        wref = (v2f){d2.x, d4.y};
    } else {  // odd-batch tail: duplicate the single element into both lanes
        const float* r = ref + 5 * i0;
        e0   = (v2f){r[0], r[0]};
        e1   = (v2f){r[1], r[1]};
        e2   = (v2f){r[2], r[2]};
        vref = (v2f){r[3], r[3]};
        wref = (v2f){r[4], r[4]};
    }

    const float dt  = DT;
    const float dt2 = dt * dt;
    const v2f dtw = dt * wref;
    const v2f dtv = dt * vref;

    // P symmetric (6 scalars per lane). P0 = diag(qf).
    v2f p00 = qf0, p01 = 0.0f, p02 = 0.0f, p11 = qf1, p12 = 0.0f, p22 = qf2;
    v2f k00 = 0.0f, k01 = 0.0f, k02 = 0.0f, k10 = 0.0f, k11 = 0.0f, k12 = 0.0f;

    // A = [[1, dtw, 0], [-dtw, 1, dtv], [0, 0, 1]],  B = [[-dt,0],[0,0],[0,-dt]]
    // Key identity: rows of (BtP@A)/(-dt) are columns 0 and 2 of T = A^T P.
    #pragma unroll
    for (int t = 0; t < HORIZON; ++t) {
        // T = A^T P  (9 FMAs)
        const v2f t00 = p00 - dtw * p01;
        const v2f t01 = p01 - dtw * p11;
        const v2f t02 = p02 - dtw * p12;
        const v2f t10 = dtw * p00 + p01;
        const v2f t11 = dtw * p01 + p11;
        const v2f t12 = dtw * p02 + p12;
        const v2f t20 = dtv * p01 + p02;
        const v2f t21 = dtv * p11 + p12;
        const v2f t22 = dtv * p12 + p22;

        // S = R + eps*I + dt^2 * [[p00, p02],[p02, p22]]
        const v2f s00 = r0e + dt2 * p00;
        const v2f s01 =       dt2 * p02;
        const v2f s11 = r1e + dt2 * p22;
        const v2f inv_det = rcp2(s00 * s11 - s01 * s01);
        const v2f c = -dt * inv_det;   // fold the -dt of BtP into K

        // K = S^{-1} (BtP @ A); M rows reused from T columns.
        const v2f cs11 = c * s11, cs01 = c * s01, cs00 = c * s00;
        k00 = cs11 * t00 - cs01 * t02;
        k01 = cs11 * t10 - cs01 * t12;
        k02 = cs11 * t20 - cs01 * t22;
        k10 = cs00 * t02 - cs01 * t00;
        k11 = cs00 * t12 - cs01 * t10;
        k12 = cs00 * t22 - cs01 * t20;

        // Acl = A - B@K  (row1 = (-dtw, 1, dtv) handled inline below)
        const v2f a00 = 1.0f + dt * k00;
        const v2f a01 = dtw  + dt * k01;
        const v2f a02 =        dt * k02;
        const v2f a20 =        dt * k10;
        const v2f a21 =        dt * k11;
        const v2f a22 = 1.0f + dt * k12;

        // P_new = Q + T @ Acl (upper triangle only)
        p00 = q0 + t00 * a00 - t01 * dtw + t02 * a20;
        p01 =      t00 * a01 + t01       + t02 * a21;
        p02 =      t00 * a02 + t01 * dtv + t02 * a22;
        p11 = q1 + t10 * a01 + t11       + t12 * a21;
        p12 =      t10 * a02 + t11 * dtv + t12 * a22;
        p22 = q2 + t20 * a02 + t21 * dtv + t22 * a22;
    }

    // delta_u = -K0 @ error; mean = u_ref + delta_u; clip
    const v2f du0 = -(k00 * e0 + k01 * e1 + k02 * e2);
    const v2f du1 = -(k10 * e0 + k11 * e1 + k12 * e2);
    v2f v = vref + du0;
    v2f w = wref + du1;
    v.x = fminf(fmaxf(v.x, -V_MAX), V_MAX);
    v.y = fminf(fmaxf(v.y, -V_MAX), V_MAX);
    w.x = fminf(fmaxf(w.x, -W_MAX), W_MAX);
    w.y = fminf(fmaxf(w.y, -W_MAX), W_MAX);

    if (pair) {
        float4* out4 = reinterpret_cast<float4*>(out);   // 16B-aligned at pair i
        out4[i] = make_float4(v.x, w.x, v.y, w.y);
    } else {
        float2* out2 = reinterpret_cast<float2*>(out);
        out2[i0] = make_float2(v.x, w.x);
    }
}

extern "C" void kernel_launch(void* const* d_in, const int* in_sizes, int n_in,
                              void* d_out, int out_size, void* d_ws, size_t ws_size,
                              hipStream_t stream) {
    const float* ref    = (const float*)d_in[0];
    const float* q_raw  = (const float*)d_in[1];
    const float* r_raw  = (const float*)d_in[2];
    const float* qf_raw = (const float*)d_in[3];
    float* out = (float*)d_out;

    const int batch = in_sizes[0] / 5;
    const int pairs = (batch + 1) / 2;
    const int block = 256;
    const int grid  = (pairs + block - 1) / block;
    lqr_kernel<<<grid, block, 0, stream>>>(ref, q_raw, r_raw, qf_raw, out, batch);
}

// Round 3
// 92.382 us; speedup vs baseline: 1.4367x; 1.0523x over previous
//
#include <hip/hip_runtime.h>
#include <math.h>

#define HORIZON 20
#define DT      0.1f
#define EPS     1e-4f
#define V_MAX   0.22f
#define W_MAX   2.8f

typedef float v2f __attribute__((ext_vector_type(2)));

__device__ __forceinline__ v2f vfma(v2f a, v2f b, v2f c) {
    return __builtin_elementwise_fma(a, b, c);   // -> v_pk_fma_f32 (guaranteed fma)
}
__device__ __forceinline__ v2f sp(float x) { return (v2f){x, x}; }

// v_rcp_f32: 1 instr, ~1ulp — plenty vs 5.6e-2 threshold.
__device__ __forceinline__ v2f rcp2(v2f x) {
    v2f r;
    r.x = __builtin_amdgcn_rcpf(x.x);
    r.y = __builtin_amdgcn_rcpf(x.y);
    return r;
}

// jax.nn.softplus(x) == max(x,0) + log1p(exp(-|x|))
__device__ __forceinline__ float softplus_f(float x) {
    return fmaxf(x, 0.0f) + log1pf(expf(-fabsf(x)));
}

// Hoist the 8 batch-uniform softplus params out of the hot kernel
// (saves ~300 transcendental-expansion instrs per thread).
__global__ void params_kernel(const float* __restrict__ q_raw,
                              const float* __restrict__ r_raw,
                              const float* __restrict__ qf_raw,
                              float* __restrict__ P) {
    if (threadIdx.x == 0 && blockIdx.x == 0) {
        P[0] = softplus_f(q_raw[0])  + EPS;
        P[1] = softplus_f(q_raw[1])  + EPS;
        P[2] = softplus_f(q_raw[2])  + EPS;
        P[3] = softplus_f(r_raw[0])  + EPS + EPS;   // R diag + eps*I2 folded
        P[4] = softplus_f(r_raw[1])  + EPS + EPS;
        P[5] = softplus_f(qf_raw[0]) + EPS;
        P[6] = softplus_f(qf_raw[1]) + EPS;
        P[7] = softplus_f(qf_raw[2]) + EPS;
    }
}

template <bool TAIL>
__global__ __launch_bounds__(256) void lqr_kernel(
    const float* __restrict__ ref,     // (B,5): e0,e1,e2,v_ref,w_ref
    const float* __restrict__ prm,     // 8 precomputed params (d_ws)
    float* __restrict__ out,           // (B,2)
    int batch)
{
    const int i = blockIdx.x * blockDim.x + threadIdx.x;  // pair index
    const int i0 = 2 * i;
    if (i0 >= batch) return;

    // Wave-uniform -> s_load_dwordx8
    const float q0 = prm[0], q1 = prm[1], q2 = prm[2];
    const float r0e = prm[3], r1e = prm[4];
    const float qf0 = prm[5], qf1 = prm[6], qf2 = prm[7];

    v2f e0, e1, e2, vref, wref;
    if (!TAIL || i0 + 1 < batch) {
        const float2* r2 = reinterpret_cast<const float2*>(ref) + 5 * i;
        const float2 d0 = r2[0], d1 = r2[1], d2 = r2[2], d3 = r2[3], d4 = r2[4];
        e0   = (v2f){d0.x, d2.y};
        e1   = (v2f){d0.y, d3.x};
        e2   = (v2f){d1.x, d3.y};
        vref = (v2f){d1.y, d4.x};
        wref = (v2f){d2.x, d4.y};
    } else {  // odd tail: duplicate single element
        const float* r = ref + 5 * i0;
        e0 = sp(r[0]); e1 = sp(r[1]); e2 = sp(r[2]); vref = sp(r[3]); wref = sp(r[4]);
    }

    const v2f dts  = sp(DT);
    const v2f dt2  = sp(DT * DT);
    const v2f ndt  = sp(-DT);
    const v2f one  = sp(1.0f);
    const v2f q0s = sp(q0), q1s = sp(q1), q2s = sp(q2);
    const v2f r0s = sp(r0e), r1s = sp(r1e);
    const v2f dtw = dts * wref;
    const v2f dtv = dts * vref;

    // P symmetric, 6 entries. P0 = diag(qf).
    v2f p00 = sp(qf0), p01 = sp(0.f), p02 = sp(0.f),
        p11 = sp(qf1), p12 = sp(0.f), p22 = sp(qf2);
    v2f k00, k01, k02, k10, k11, k12;

    // A = I + dt*[[0,w,0],[-w,0,v],[0,0,0]],  B = [[-dt,0],[0,0],[0,-dt]]
    // Identity: rows of (BtP@A)/(-dt) are columns 0,2 of T = A^T P.
    #pragma unroll
    for (int t = 0; t < HORIZON; ++t) {
        // T = A^T P  (9 pk_fma)
        const v2f t00 = vfma(-dtw, p01, p00);
        const v2f t01 = vfma(-dtw, p11, p01);
        const v2f t02 = vfma(-dtw, p12, p02);
        const v2f t10 = vfma(dtw, p00, p01);
        const v2f t11 = vfma(dtw, p01, p11);
        const v2f t12 = vfma(dtw, p02, p12);
        const v2f t20 = vfma(dtv, p01, p02);
        const v2f t21 = vfma(dtv, p11, p12);
        const v2f t22 = vfma(dtv, p12, p22);

        // S = R + eps*I + dt^2*[[p00,p02],[p02,p22]]
        const v2f s00 = vfma(dt2, p00, r0s);
        const v2f s01 = dt2 * p02;
        const v2f s11 = vfma(dt2, p22, r1s);
        const v2f det = vfma(s00, s11, -(s01 * s01));
        const v2f c   = ndt * rcp2(det);          // fold -dt of BtP into K
        const v2f cs11 = c * s11, cs01 = c * s01, cs00 = c * s00;

        // K = S^{-1} (BtP@A), rows from T columns
        k00 = vfma(cs11, t00, -(cs01 * t02));
        k01 = vfma(cs11, t10, -(cs01 * t12));
        k02 = vfma(cs11, t20, -(cs01 * t22));
        k10 = vfma(cs00, t02, -(cs01 * t00));
        k11 = vfma(cs00, t12, -(cs01 * t10));
        k12 = vfma(cs00, t22, -(cs01 * t20));

        // Acl = A - B@K  (row1 = (-dtw, 1, dtv) inlined below)
        const v2f a00 = vfma(dts, k00, one);
        const v2f a01 = vfma(dts, k01, dtw);
        const v2f a02 = dts * k02;
        const v2f a20 = dts * k10;
        const v2f a21 = dts * k11;
        const v2f a22 = vfma(dts, k12, one);

        // P_new = Q + T @ Acl (upper triangle)
        p00 = vfma(t02, a20, vfma(t01, -dtw, vfma(t00, a00, q0s)));
        p01 = vfma(t02, a21, vfma(t00, a01, t01));
        p02 = vfma(t02, a22, vfma(t01, dtv, t00 * a02));
        p11 = vfma(t12, a21, vfma(t10, a01, t11 + q1s));
        p12 = vfma(t12, a22, vfma(t11, dtv, t10 * a02));
        p22 = vfma(t22, a22, vfma(t21, dtv, vfma(t20, a02, q2s)));
    }

    // delta_u = -K0 @ error; mean = u_ref + delta_u; clip
    const v2f s0 = vfma(k02, e2, vfma(k01, e1, k00 * e0));
    const v2f s1 = vfma(k12, e2, vfma(k11, e1, k10 * e0));
    v2f v = vref - s0;
    v2f w = wref - s1;
    v = __builtin_elementwise_min(__builtin_elementwise_max(v, sp(-V_MAX)), sp(V_MAX));
    w = __builtin_elementwise_min(__builtin_elementwise_max(w, sp(-W_MAX)), sp(W_MAX));

    if (!TAIL || i0 + 1 < batch) {
        float4* out4 = reinterpret_cast<float4*>(out);
        out4[i] = make_float4(v.x, w.x, v.y, w.y);
    } else {
        float2* out2 = reinterpret_cast<float2*>(out);
        out2[i0] = make_float2(v.x, w.x);
    }
}

extern "C" void kernel_launch(void* const* d_in, const int* in_sizes, int n_in,
                              void* d_out, int out_size, void* d_ws, size_t ws_size,
                              hipStream_t stream) {
    const float* ref    = (const float*)d_in[0];
    const float* q_raw  = (const float*)d_in[1];
    const float* r_raw  = (const float*)d_in[2];
    const float* qf_raw = (const float*)d_in[3];
    float* out = (float*)d_out;
    float* prm = (float*)d_ws;

    const int batch = in_sizes[0] / 5;
    const int pairs = (batch + 1) / 2;
    const int block = 256;
    const int grid  = (pairs + block - 1) / block;

    params_kernel<<<1, 64, 0, stream>>>(q_raw, r_raw, qf_raw, prm);
    if (batch & 1)
        lqr_kernel<true><<<grid, block, 0, stream>>>(ref, prm, out, batch);
    else
        lqr_kernel<false><<<grid, block, 0, stream>>>(ref, prm, out, batch);
}